// Round 4
// baseline (2848.644 us; speedup 1.0000x reference)
//
#include <hip/hip_runtime.h>
#include <hip/hip_bf16.h>
#include <stdint.h>

// Problem constants
#define B_SZ   64
#define L_SEQ  512
#define DIN    1024
#define HDIM   1024
// out layout: outputs [64*512*1024], h_fin [64*1024], c_fin [64*1024]
#define OUT_HFIN 33554432L
#define OUT_CFIN 33619968L

typedef float  f32x4 __attribute__((ext_vector_type(4)));
typedef short  s16x8 __attribute__((ext_vector_type(8)));
typedef unsigned short u16;
typedef unsigned int   u32;
typedef unsigned long long u64;

// ---- workspace layout (bytes) ----
// Mailbox REUSES the wx region (dead after xproj_gemm); zeroed by mbzero_kernel
// which runs between xproj_gemm and lstm_rec (stream-ordered).
#define OFF_XBF   0ULL
#define OFF_WX    67108864ULL
#define OFF_MB    67108864ULL      // 2 x 256KB tag-mailbox (ping-pong)
#define OFF_WH    75497472ULL
#define OFF_XPROJ 83886080ULL

static __device__ __forceinline__ u16 f2bf(float f) {
    __hip_bfloat16 h = __float2bfloat16(f);
    return *reinterpret_cast<u16*>(&h);
}
static __device__ __forceinline__ float bf2f(u16 u) {
    union { uint32_t i; float f; } v;
    v.i = ((uint32_t)u) << 16;
    return v.f;
}
static __device__ __forceinline__ float fsigmoid(float x) {
    return __builtin_amdgcn_rcpf(1.0f + __expf(-x));
}
static __device__ __forceinline__ float ftanh(float x) {
    return 1.0f - 2.0f * __builtin_amdgcn_rcpf(1.0f + __expf(2.0f * x));
}
// async global->LDS, 16B per lane. LDS ptr must be wave-uniform (HW writes
// base + lane*16); global ptr is per-lane.
static __device__ __forceinline__ void gload_lds16(const u16* g, u16* l) {
    __builtin_amdgcn_global_load_lds((const __attribute__((address_space(1))) void*)g,
                                     (__attribute__((address_space(3))) void*)l, 16, 0, 0);
}

// ============================ prep: fp32 -> bf16 ============================
__global__ void prep_kernel(const float* __restrict__ x, const float* __restrict__ W,
                            u16* __restrict__ xbf, u16* __restrict__ wx,
                            u16* __restrict__ wh) {
    long tid = (long)blockIdx.x * blockDim.x + threadIdx.x;
    long stride = (long)gridDim.x * blockDim.x;
    const long NX4 = 33554432 / 4;
    for (long i = tid; i < NX4; i += stride) {
        float4 v = ((const float4*)x)[i];
        ushort4 o;
        o.x = f2bf(v.x); o.y = f2bf(v.y); o.z = f2bf(v.z); o.w = f2bf(v.w);
        ((ushort4*)xbf)[i] = o;
    }
    const long NW4 = 8388608 / 4;
    for (long i = tid; i < NW4; i += stride) {
        float4 v = ((const float4*)W)[i];
        long f = i * 4;
        long n = f >> 11;        // row of W (2048 wide)
        long c = f & 2047;
        ushort4 o;
        o.x = f2bf(v.x); o.y = f2bf(v.y); o.z = f2bf(v.z); o.w = f2bf(v.w);
        u16* dst = (c < 1024) ? &wh[n * 1024 + c] : &wx[n * 1024 + (c - 1024)];
        *(ushort4*)dst = o;
    }
}

// ============ zero the tag-mailbox (runs AFTER xproj_gemm reads wx) =========
__global__ void mbzero_kernel(float4* __restrict__ mb) {
    int i = blockIdx.x * blockDim.x + threadIdx.x;   // 128*256 = 32768 * 16B = 512KB
    mb[i] = make_float4(0.f, 0.f, 0.f, 0.f);
}

// ==================== phase 1: x_proj = x @ Wx^T + b (bf16 out) =============
// m97-structure: global_load_lds dwordx4 staging + double-buffered LDS,
// one barrier per K-step.
__global__ __launch_bounds__(256) void xproj_gemm(const u16* __restrict__ xbf,
                                                  const u16* __restrict__ wxbf,
                                                  const float* __restrict__ bias,
                                                  u16* __restrict__ xproj) {
    __shared__ u16 As[2][128 * 32];
    __shared__ u16 Bs[2][128 * 32];
    const int tid  = threadIdx.x;
    const int lane = tid & 63;
    const int w    = tid >> 6;
    const int wm   = w >> 1, wn = w & 1;
    const int l15  = lane & 15, quad = lane >> 4;
    const int m0 = blockIdx.y * 128;
    const int n0 = blockIdx.x * 128;

    const u16* ga = xbf  + (long)(m0 + (tid >> 2)) * 1024 + (tid & 3) * 8;
    const u16* gb = wxbf + (long)(n0 + (tid >> 2)) * 1024 + (tid & 3) * 8;

    f32x4 acc[4][4];
#pragma unroll
    for (int i = 0; i < 4; ++i)
#pragma unroll
        for (int j = 0; j < 4; ++j) acc[i][j] = 0.0f;

#define STAGE(buf, k0)                                                    \
    do {                                                                  \
        gload_lds16(ga + (k0),         &As[buf][w * 512]);                \
        gload_lds16(ga + 65536 + (k0), &As[buf][2048 + w * 512]);         \
        gload_lds16(gb + (k0),         &Bs[buf][w * 512]);                \
        gload_lds16(gb + 65536 + (k0), &Bs[buf][2048 + w * 512]);         \
    } while (0)

    STAGE(0, 0);
    __syncthreads();

    for (int kt = 0; kt < 32; ++kt) {
        const int cur = kt & 1;
        if (kt < 31) STAGE(cur ^ 1, (kt + 1) * 32);

        s16x8 af[4], bfr[4];
#pragma unroll
        for (int mt = 0; mt < 4; ++mt)
            af[mt] = *(const s16x8*)&As[cur][(wm * 64 + mt * 16 + l15) * 32 + quad * 8];
#pragma unroll
        for (int nt = 0; nt < 4; ++nt)
            bfr[nt] = *(const s16x8*)&Bs[cur][(wn * 64 + nt * 16 + l15) * 32 + quad * 8];
#pragma unroll
        for (int mt = 0; mt < 4; ++mt)
#pragma unroll
            for (int nt = 0; nt < 4; ++nt)
                acc[mt][nt] = __builtin_amdgcn_mfma_f32_16x16x32_bf16(af[mt], bfr[nt], acc[mt][nt], 0, 0, 0);

        __syncthreads();
    }
#undef STAGE

#pragma unroll
    for (int nt = 0; nt < 4; ++nt) {
        int n = n0 + wn * 64 + nt * 16 + l15;
        float bv = bias[n];
#pragma unroll
        for (int mt = 0; mt < 4; ++mt) {
            int mbase = m0 + wm * 64 + mt * 16 + quad * 4;
#pragma unroll
            for (int r = 0; r < 4; ++r)
                xproj[(long)(mbase + r) * 4096 + n] = f2bf(acc[mt][nt][r] + bv);
        }
    }
}

// ======================= phase 2: sequential recurrence =====================
// 256 blocks: g = bid&3 (16 batch rows), jc = bid>>2 (16 h-cols).
// Wave w covers K-slice [256w, 256w+256) for all 4 gates.
//
// TAG-MAILBOX v2: layout [buf 2][g 4][colpair 512][row 16] u64 slots
//   slot = { lo32: 2 x bf16 h-cols, hi32: tag }; 8B-aligned -> single-copy
//   atomic; one relaxed store publishes data+validity.
//   * consumer loads its 32 slots DIRECTLY into MFMA A-fragments (lo32s of
//     4 consecutive slots = one s16x8). No LDS h-stage, no ds_read.
//     [cp][row] layout -> per-instruction addresses span 4x128B segments.
//   * SELECTIVE retry: per-lane 32-bit stale mask; retries reload only
//     stale slots (exec-masked; skipped entirely when mask==0 wave-wide).
//   * xp prefetch for t+1 issued at TOP of step t: its HBM latency drains
//     inside the acquire wait (vmcnt is FIFO -- issuing it after the
//     publish would put it in front of next step's tag loads).
//   Ping-pong by t&1; safety: producer overwrites parity-p slots of h_{t-1}
//   only at step t+1, gated (via its own barrier joining all 4 waves' tag
//   waits, which cover all 64 producers of the group) on every block having
//   published tag t+1, which happens only after that block's reads of
//   h_{t-1} completed. part[] double-buffered by t&1 -> the single barrier
//   is race-free under wave skew.
__global__ __launch_bounds__(256, 1) void lstm_rec(const u16* __restrict__ whbf,
                                                   const u16* __restrict__ xproj,
                                                   u64* __restrict__ mbbuf,
                                                   float* __restrict__ out) {
    __shared__ float part[2][4][16][4][17];   // [buf][gate][row][wave][col+pad]

    const int tid  = threadIdx.x;
    const int w    = tid >> 6;
    const int lane = tid & 63;
    const int l15  = lane & 15, quad = lane >> 4;
    const int g    = blockIdx.x & 3;
    const int jc   = blockIdx.x >> 2;
    const int bbase = g * 16;
    const int crow = 4 * w + quad;            // elementwise cell row (0..15)
    const int ccol = l15;                     // elementwise cell col (0..15)

    // Wh fragments: wave w holds K-slice [w*256, w*256+256) for all 4 gates.
    s16x8 bfrag[4][8];
#pragma unroll
    for (int gate = 0; gate < 4; ++gate) {
        const long nrow = (long)gate * 1024 + jc * 16 + l15;
#pragma unroll
        for (int kc = 0; kc < 8; ++kc)
            bfrag[gate][kc] = *(const s16x8*)&whbf[nrow * 1024 + w * 256 + kc * 32 + quad * 8];
    }

    float c_reg = 0.0f;
    // mailbox u64 index: buf*32768 + g*8192 + cp*16 + row, cp in [0,512)
    // consumer: tmp[i] = slot[cp = w*128 + (i>>2)*16 + quad*4 + (i&3)][row=l15]
    const u64* mbrd0 = mbbuf + (u64)g * 8192 + w * 2048 + quad * 64 + l15;
    // producer (even l15 lanes): slot[cp = jc*8 + l15/2][row = crow]
    u64* mbwr0 = mbbuf + (u64)g * 8192 + jc * 128 + (l15 >> 1) * 16 + 4 * w + quad;

    // xp for t=0 preloaded; per step, t+1's xp is issued at the top.
    const u16* xpcell = xproj + (long)(bbase + crow) * 512 * 4096 + jc * 16 + ccol;
    float xp[4], xpn[4];
#pragma unroll
    for (int gate = 0; gate < 4; ++gate)
        xp[gate] = bf2f(xpcell[(long)gate * 1024]);

    for (int t = 0; t < 512; ++t) {
        // ---- xp prefetch for t+1 (issued FIRST; drains under acquire wait) ----
        if (t < 511) {
#pragma unroll
            for (int gate = 0; gate < 4; ++gate)
                xpn[gate] = bf2f(xpcell[((long)t + 1) * 4096 + (long)gate * 1024]);
        }

        // ---- acquire h_{t-1}: tagged loads straight into fragments ----
        u64 tmp[32];
        if (t == 0) {
#pragma unroll
            for (int i = 0; i < 32; ++i) tmp[i] = 0ULL;
        } else {
            const u64* mbr = mbrd0 + ((t + 1) & 1) * 32768;
#pragma unroll
            for (int i = 0; i < 32; ++i)
                tmp[i] = __hip_atomic_load(&mbr[(i >> 2) * 256 + (i & 3) * 16],
                                           __ATOMIC_RELAXED, __HIP_MEMORY_SCOPE_AGENT);
            u32 bm = 0;
#pragma unroll
            for (int i = 0; i < 32; ++i)
                bm |= ((u32)(tmp[i] >> 32) != (u32)t) ? (1u << i) : 0u;
            while (__ballot(bm != 0) != 0ULL) {
#pragma unroll
                for (int i = 0; i < 32; ++i)
                    if (bm & (1u << i))
                        tmp[i] = __hip_atomic_load(&mbr[(i >> 2) * 256 + (i & 3) * 16],
                                                   __ATOMIC_RELAXED, __HIP_MEMORY_SCOPE_AGENT);
                u32 nbm = 0;
#pragma unroll
                for (int i = 0; i < 32; ++i)
                    nbm |= ((u32)(tmp[i] >> 32) != (u32)t) ? (1u << i) : 0u;
                bm = nbm;
            }
        }

        // ---- MFMA: K-slice per wave, 4 gate accumulators, fragments from regs ----
        f32x4 acc[4];
#pragma unroll
        for (int gate = 0; gate < 4; ++gate) acc[gate] = 0.0f;
#pragma unroll
        for (int kc = 0; kc < 8; ++kc) {
            union { u32 u[4]; s16x8 v; } a;
            a.u[0] = (u32)tmp[kc * 4 + 0];
            a.u[1] = (u32)tmp[kc * 4 + 1];
            a.u[2] = (u32)tmp[kc * 4 + 2];
            a.u[3] = (u32)tmp[kc * 4 + 3];
            acc[0] = __builtin_amdgcn_mfma_f32_16x16x32_bf16(a.v, bfrag[0][kc], acc[0], 0, 0, 0);
            acc[1] = __builtin_amdgcn_mfma_f32_16x16x32_bf16(a.v, bfrag[1][kc], acc[1], 0, 0, 0);
            acc[2] = __builtin_amdgcn_mfma_f32_16x16x32_bf16(a.v, bfrag[2][kc], acc[2], 0, 0, 0);
            acc[3] = __builtin_amdgcn_mfma_f32_16x16x32_bf16(a.v, bfrag[3][kc], acc[3], 0, 0, 0);
        }
        // partials: D row = quad*4+r, col = l15  (2-way-free layout)
#pragma unroll
        for (int gate = 0; gate < 4; ++gate)
#pragma unroll
            for (int r = 0; r < 4; ++r)
                part[t & 1][gate][quad * 4 + r][w][l15] = acc[gate][r];
        __syncthreads();   // the ONLY block barrier per step

        // ---- elementwise: each lane owns one (crow, ccol) cell ----
        float gv[4];
#pragma unroll
        for (int gate = 0; gate < 4; ++gate) {
            float p0 = part[t & 1][gate][crow][0][ccol];
            float p1 = part[t & 1][gate][crow][1][ccol];
            float p2 = part[t & 1][gate][crow][2][ccol];
            float p3 = part[t & 1][gate][crow][3][ccol];
            gv[gate] = ((p0 + p1) + (p2 + p3)) + xp[gate];
        }
        float fv = fsigmoid(gv[0]);
        float iv = fsigmoid(gv[1]);
        float gg = ftanh   (gv[2]);
        float ov = fsigmoid(gv[3]);
        c_reg = fv * c_reg + iv * gg;
        float h = ov * ftanh(c_reg);

        if (t < 511) {
            // publish: pair cols via shfl, ONE tagged u64 store per even lane.
            float hn = __shfl_xor(h, 1);
            if ((l15 & 1) == 0) {
                u32 data = (u32)f2bf(h) | ((u32)f2bf(hn) << 16);
                u64 slot = ((u64)(u32)(t + 1) << 32) | (u64)data;
                __hip_atomic_store(mbwr0 + (t & 1) * 32768, slot,
                                   __ATOMIC_RELAXED, __HIP_MEMORY_SCOPE_AGENT);
            }
        }

        long bg = bbase + crow;
        long j  = jc * 16 + ccol;
        out[(bg * 512 + t) * 1024 + j] = h;
        if (t == 511) {
            out[OUT_HFIN + bg * 1024 + j] = h;
            out[OUT_CFIN + bg * 1024 + j] = c_reg;
        }
#pragma unroll
        for (int gate = 0; gate < 4; ++gate) xp[gate] = xpn[gate];
    }
}

// ================================ launcher =================================
extern "C" void kernel_launch(void* const* d_in, const int* in_sizes, int n_in,
                              void* d_out, int out_size, void* d_ws, size_t ws_size,
                              hipStream_t stream) {
    const float* x    = (const float*)d_in[0];
    const float* W    = (const float*)d_in[1];
    const float* bias = (const float*)d_in[2];
    float* out = (float*)d_out;
    char*  ws  = (char*)d_ws;

    u16* xbf   = (u16*)(ws + OFF_XBF);
    u16* wx    = (u16*)(ws + OFF_WX);
    u16* wh    = (u16*)(ws + OFF_WH);
    u16* xproj = (u16*)(ws + OFF_XPROJ);
    u64* mb    = (u64*)(ws + OFF_MB);

    hipLaunchKernelGGL(prep_kernel, dim3(2048), dim3(256), 0, stream, x, W, xbf, wx, wh);
    hipLaunchKernelGGL(xproj_gemm, dim3(32, 256), dim3(256), 0, stream, xbf, wx, bias, xproj);
    hipLaunchKernelGGL(mbzero_kernel, dim3(128), dim3(256), 0, stream, (float4*)mb);
    hipLaunchKernelGGL(lstm_rec, dim3(256), dim3(256), 0, stream, wh, xproj, mb, out);
}